// Round 9
// baseline (202.268 us; speedup 1.0000x reference)
//
#include <hip/hip_runtime.h>

// DEC Student-t soft assignment, ALPHA=1 -> q_ij = 1/(1+d2_ij), row-normalized.
// d2 = ||h||^2 + ||c||^2 - 2 h.c ; cross term via bf16 MFMA, h_sq/c_sq exact fp32.
//
// R8 -> R9: occupancy attack. All 8 prior rounds ran ~2 resident blocks/CU
// (Occupancy 21-28%) with barrier-coupled waves = ~2 independent streams; per
// block-K-step the HW pipes need only ~400 cyc but measured ~1400 -> latency-
// bound, not throughput-bound. R9: 128^2 tile, SINGLE 16 KB LDS buffer,
// 2-deep REGISTER prefetch (global->reg dwordx4, ds_write next tile after a
// barrier; compiler inserts counted vmcnt automatically - no inline asm).
// 16 KB LDS + ~155 VGPR => 3 blocks/CU, 3 independent barrier domains.
// Granule-XOR swizzle p=g^((g>>3)&7) on BOTH ds_write and ds_read (involution,
// 0 conflicts verified R2-R8).

typedef unsigned short u16;
typedef __attribute__((ext_vector_type(8))) short bf16x8;  // 8 bf16 = 4 VGPRs
typedef __attribute__((ext_vector_type(4))) float f32x4;

#define N_ROWS 32768
#define K_CENT 1000
#define KP     1024   // padded centroid count
#define DDIM   1024
#define NT     32     // K-tiles of BK=32

__device__ __forceinline__ u16 f2bf(float x) {
  unsigned u = __float_as_uint(x);
  u += 0x7fffu + ((u >> 16) & 1u);   // round-to-nearest-even
  return (u16)(u >> 16);
}

// ---------------- prep kernels ----------------

__global__ __launch_bounds__(256) void prep_h(const float* __restrict__ h,
                                              u16* __restrict__ hb,
                                              float* __restrict__ hsq,
                                              float* __restrict__ rowsum) {
  const int row = blockIdx.x;
  const int t = threadIdx.x;
  const float4 v = reinterpret_cast<const float4*>(h + (size_t)row * DDIM)[t];
  ushort4 b;
  b.x = f2bf(v.x); b.y = f2bf(v.y); b.z = f2bf(v.z); b.w = f2bf(v.w);
  reinterpret_cast<ushort4*>(hb + (size_t)row * DDIM)[t] = b;
  float ss = v.x * v.x + v.y * v.y + v.z * v.z + v.w * v.w;
#pragma unroll
  for (int m = 1; m < 64; m <<= 1) ss += __shfl_xor(ss, m);
  __shared__ float sbuf[4];
  if ((t & 63) == 0) sbuf[t >> 6] = ss;
  __syncthreads();
  if (t == 0) {
    hsq[row] = sbuf[0] + sbuf[1] + sbuf[2] + sbuf[3];
    rowsum[row] = 0.0f;
  }
}

__global__ __launch_bounds__(256) void prep_c(const float* __restrict__ c,
                                              u16* __restrict__ cb,
                                              float* __restrict__ csq) {
  const int row = blockIdx.x;
  const int t = threadIdx.x;
  if (row < K_CENT) {
    const float4 v = reinterpret_cast<const float4*>(c + (size_t)row * DDIM)[t];
    ushort4 b;
    b.x = f2bf(v.x); b.y = f2bf(v.y); b.z = f2bf(v.z); b.w = f2bf(v.w);
    reinterpret_cast<ushort4*>(cb + (size_t)row * DDIM)[t] = b;
    float ss = v.x * v.x + v.y * v.y + v.z * v.z + v.w * v.w;
#pragma unroll
    for (int m = 1; m < 64; m <<= 1) ss += __shfl_xor(ss, m);
    __shared__ float sbuf[4];
    if ((t & 63) == 0) sbuf[t >> 6] = ss;
    __syncthreads();
    if (t == 0) csq[row] = sbuf[0] + sbuf[1] + sbuf[2] + sbuf[3];
  } else {
    ushort4 z; z.x = z.y = z.z = z.w = 0;
    reinterpret_cast<ushort4*>(cb + (size_t)row * DDIM)[t] = z;
    if (t == 0) csq[row] = 1e30f;  // pad rows: q ~ 1/(1+1e30) ~ 0
  }
}

// ---------------- main GEMM + q epilogue ----------------
// Tile = 128 rows x 32 k bf16 per matrix = 512 granules of 16 B each.
// Logical granule g = 4*row + j (j = 16B chunk in row). LDS position
// p = g ^ ((g>>3)&7) (involution). Thread tid owns granules {tid, tid+256}
// of A and of B: global reads are 4-granule (64 B) row runs; ds_writes are
// conflict-free (each 16-lane group covers all 8 bank-quads twice).

__global__ __launch_bounds__(256) void gemm_q(const u16* __restrict__ hb,
                                              const u16* __restrict__ cb,
                                              const float* __restrict__ hsq,
                                              const float* __restrict__ csq,
                                              float* __restrict__ out,
                                              float* __restrict__ rowsum) {
  __shared__ u16 SM[8192];   // 16 KB: As = SM[0..4095], Bs = SM[4096..8191]

  const int bid = blockIdx.x;
  // XCD swizzle (2048 % 8 == 0)
  const int swz = ((bid & 7) << 8) | (bid >> 3);
  const int bcol = swz & 7;    // 8 column blocks of 128
  const int brow = swz >> 3;   // 256 row panels of 128

  const int t = threadIdx.x;
  const int w = t >> 6;
  const int l = t & 63;
  const int wr = w >> 1;       // wave row (0..1), 64 rows each
  const int wc = w & 1;        // wave col (0..1), 64 cols each

  const u16* gA = hb + (size_t)brow * 128 * DDIM;
  const u16* gB = cb + (size_t)bcol * 128 * DDIM;

  // per-thread staged granules and their swizzled LDS slots
  const int g0 = t, g1 = t + 256;
  const int p0 = g0 ^ ((g0 >> 3) & 7);
  const int p1 = g1 ^ ((g1 >> 3) & 7);
  const size_t ga0 = (size_t)(g0 >> 2) * DDIM + (g0 & 3) * 8;
  const size_t ga1 = (size_t)(g1 >> 2) * DDIM + (g1 & 3) * 8;

#define GLOAD(RA, RB, T)                                                       \
  {                                                                            \
    const int kk = (T) * 32;                                                   \
    RA[0] = *(const bf16x8*)(gA + ga0 + kk);                                   \
    RA[1] = *(const bf16x8*)(gA + ga1 + kk);                                   \
    RB[0] = *(const bf16x8*)(gB + ga0 + kk);                                   \
    RB[1] = *(const bf16x8*)(gB + ga1 + kk);                                   \
  }
#define SWRITE(RA, RB)                                                         \
  {                                                                            \
    *(bf16x8*)&SM[p0 << 3] = RA[0];                                            \
    *(bf16x8*)&SM[p1 << 3] = RA[1];                                            \
    *(bf16x8*)&SM[4096 + (p0 << 3)] = RB[0];                                   \
    *(bf16x8*)&SM[4096 + (p1 << 3)] = RB[1];                                   \
  }

  // read-side fragment offsets (verified involution)
  const int hi = l >> 4;
  int aOff[4], bOff[4];
#pragma unroll
  for (int m = 0; m < 4; ++m) {
    const int ga = ((wr * 64 + m * 16 + (l & 15)) << 2) | hi;
    const int gb = ((wc * 64 + m * 16 + (l & 15)) << 2) | hi;
    aOff[m] = (ga ^ ((ga >> 3) & 7)) << 3;
    bOff[m] = 4096 + ((gb ^ ((gb >> 3) & 7)) << 3);
  }

  f32x4 acc[4][4] = {};
  bf16x8 pAa[2], pBa[2], pAb[2], pBb[2];

  // prologue: tile0 -> setA, tile1 -> setB, write tile0 to LDS
  GLOAD(pAa, pBa, 0)
  GLOAD(pAb, pBb, 1)
  SWRITE(pAa, pBa)          // compiler waits (counted) on tile0's loads only
  __syncthreads();

  // Invariant at iter T: LDS = tile T; SN = tile T+1 (regs); SF = free.
#define ITER(T, SNa, SNb, SFa, SFb)                                            \
  {                                                                            \
    if ((T) + 2 < NT) GLOAD(SFa, SFb, (T) + 2)                                 \
    bf16x8 aF[4], bF[4];                                                       \
    _Pragma("unroll") for (int m = 0; m < 4; ++m)                              \
        aF[m] = *(const bf16x8*)&SM[aOff[m]];                                  \
    _Pragma("unroll") for (int n = 0; n < 4; ++n)                              \
        bF[n] = *(const bf16x8*)&SM[bOff[n]];                                  \
    _Pragma("unroll") for (int m = 0; m < 4; ++m)                              \
      _Pragma("unroll") for (int n = 0; n < 4; ++n)                            \
        acc[m][n] = __builtin_amdgcn_mfma_f32_16x16x32_bf16(aF[m], bF[n],      \
                                                            acc[m][n], 0, 0, 0); \
    __builtin_amdgcn_s_barrier();                                              \
    if ((T) + 1 < NT) { SWRITE(SNa, SNb) __builtin_amdgcn_s_barrier(); }       \
  }

#pragma unroll 1
  for (int kt = 0; kt < NT; kt += 2) {
    ITER(kt,     pAb, pBb, pAa, pBa)
    ITER(kt + 1, pAa, pBa, pAb, pBb)
  }
#undef ITER
#undef GLOAD
#undef SWRITE

  // ---- epilogue: q, rowsum atomics, scatter store (R2-verified) ----
  const int gi0 = brow * 128 + wr * 64;
  const int gj0 = bcol * 128 + wc * 64;
  const int lr = (l >> 4) << 2;
  const int lc = l & 15;

#pragma unroll
  for (int m = 0; m < 4; ++m) {
    float hs[4];
#pragma unroll
    for (int r = 0; r < 4; ++r) hs[r] = hsq[gi0 + m * 16 + lr + r];
    float rs[4] = {0.f, 0.f, 0.f, 0.f};
#pragma unroll
    for (int n = 0; n < 4; ++n) {
      const int gj = gj0 + n * 16 + lc;
      const float cs = csq[gj];
#pragma unroll
      for (int r = 0; r < 4; ++r) {
        float d2 = hs[r] + cs - 2.0f * acc[m][n][r];
        d2 = fmaxf(d2, 0.0f);
        const float qv = 1.0f / (1.0f + d2);
        rs[r] += qv;
        if (gj < K_CENT)
          out[(size_t)(gi0 + m * 16 + lr + r) * K_CENT + gj] = qv;
      }
    }
#pragma unroll
    for (int r = 0; r < 4; ++r) {
      float v = rs[r];
      v += __shfl_xor(v, 1);
      v += __shfl_xor(v, 2);
      v += __shfl_xor(v, 4);
      v += __shfl_xor(v, 8);
      if (lc == 0) atomicAdd(&rowsum[gi0 + m * 16 + lr + r], v);
    }
  }
}

// ---------------- normalization ----------------

__global__ __launch_bounds__(256) void norm_k(float* __restrict__ out,
                                              const float* __restrict__ rowsum) {
  const int row = blockIdx.x;
  const int t = threadIdx.x;
  if (t < 250) {  // 1000 floats = 250 float4 per row (4000 B, 16B-aligned)
    const float inv = 1.0f / rowsum[row];
    float4* p = reinterpret_cast<float4*>(out) + (size_t)row * 250 + t;
    float4 v = *p;
    v.x *= inv; v.y *= inv; v.z *= inv; v.w *= inv;
    *p = v;
  }
}

// ---------------- launch ----------------

extern "C" void kernel_launch(void* const* d_in, const int* in_sizes, int n_in,
                              void* d_out, int out_size, void* d_ws, size_t ws_size,
                              hipStream_t stream) {
  const float* h   = (const float*)d_in[0];
  const float* cen = (const float*)d_in[1];
  float* out = (float*)d_out;
  char* ws = (char*)d_ws;

  u16*   cb     = (u16*)(ws);                           // 2 MB
  u16*   hb     = (u16*)(ws + 2097152);                 // 64 MB
  float* hsq    = (float*)(ws + 2097152 + 67108864);    // 128 KB
  float* csq    = (float*)(ws + 2097152 + 67108864 + 131072);   // 4 KB
  float* rowsum = (float*)(ws + 2097152 + 67108864 + 131072 + 4096); // 128 KB

  prep_c<<<KP, 256, 0, stream>>>(cen, cb, csq);
  prep_h<<<N_ROWS, 256, 0, stream>>>(h, hb, hsq, rowsum);
  gemm_q<<<(N_ROWS / 128) * (KP / 128), 256, 0, stream>>>(hb, cb, hsq, csq, out, rowsum);
  norm_k<<<N_ROWS, 256, 0, stream>>>(out, rowsum);
}